// Round 3
// baseline (38614.536 us; speedup 1.0000x reference)
//
#include <hip/hip_runtime.h>
#include <math.h>

// ---------------------------------------------------------------------------
// Model_49675591746044: VQ + 6-layer post-LN transformer decoder.
// Round 3: runtime input-dtype detection (bf16 vs fp32), dual-path loads,
// output dtype follows input dtype. fp32 compute in ws; flash attention.
// ---------------------------------------------------------------------------

#define THREEFRY_PARTITIONABLE 1   // flip to 0 if VQ rows mismatch (finite O(1) absmax)

typedef unsigned short u16;
typedef unsigned int   u32;
typedef unsigned long long u64;

constexpr int NB  = 16;
constexpr int NS  = 512;
constexpr int ND  = 768;
constexpr int NK  = 8192;
constexpr int NH  = 8;
constexpr int NL  = 6;
constexpr int NF  = 2048;
constexpr int NTOK = NB * NS;   // 8192
constexpr int NDH  = ND / NH;   // 96
#define NEGV (-1e9f)

__device__ __forceinline__ float b2f(u16 u) { return __uint_as_float(((u32)u) << 16); }
__device__ __forceinline__ u16 f2b(float f) {
  u32 u = __float_as_uint(f);
  u32 r = (u + 0x7FFFu + ((u >> 16) & 1u)) >> 16;
  return (u16)r;
}
// generic scalar input load: element i of a bf16-or-fp32 array
__device__ __forceinline__ float ldv(const void* p, size_t i, int isbf) {
  return isbf ? b2f(((const u16*)p)[i]) : ((const float*)p)[i];
}

// ---------------- dtype detection ----------------
// bf16 N(0,1) data: exponent field in [100,134] (|v| in [2^-27, 128]) ~always.
// fp32 data read as u16 halves: low halves have uniform exponents -> ~45% wild.
__global__ void k_detect(const void* x, int* flag) {
  if (threadIdx.x == 0 && blockIdx.x == 0) {
    const u16* p = (const u16*)x;
    int wild = 0;
    for (int i = 0; i < 1024; i++) {
      u16 u = p[i];
      u32 e = (u >> 7) & 0xFF;
      if (!(u == 0 || u == 0x8000u || (e >= 100 && e <= 134))) wild++;
    }
    *flag = (wild < 64) ? 1 : 0;   // 1 = bf16 inputs
  }
}

// ---------------- reductions (blockDim.x == 256) ----------------
__device__ __forceinline__ float blockReduceSum256(float v, float* s) {
  int t = threadIdx.x;
  s[t] = v; __syncthreads();
  #pragma unroll
  for (int off = 128; off > 0; off >>= 1) {
    if (t < off) s[t] += s[t + off];
    __syncthreads();
  }
  float r = s[0]; __syncthreads();
  return r;
}

// ---------------- pad mask + z_e (fp32) + |x|^2 ----------------
__global__ __launch_bounds__(256) void k_pad_z(
    const void* __restrict__ x, float* __restrict__ z,
    float* __restrict__ xn2, int* __restrict__ padf, const int* __restrict__ flag) {
  __shared__ float sred[256];
  int r = blockIdx.x, t = threadIdx.x;
  int isbf = *flag;
  size_t base = (size_t)r * ND;
  float a0 = ldv(x, base + t, isbf);
  float a1 = ldv(x, base + t + 256, isbf);
  float a2 = ldv(x, base + t + 512, isbf);
  float ss = blockReduceSum256(a0 * a0 + a1 * a1 + a2 * a2, sred);
  int pad = (sqrtf(ss) <= 1e-6f) ? 1 : 0;
  if (pad) { a0 = 0.f; a1 = 0.f; a2 = 0.f; }
  float* zr = z + base;
  zr[t] = a0; zr[t + 256] = a1; zr[t + 512] = a2;
  if (t == 0) { xn2[r] = pad ? 0.f : ss; padf[r] = pad; }
}

// ---------------- codebook -> fp32 copy + |c|^2 ----------------
__global__ __launch_bounds__(256) void k_cb(
    const void* __restrict__ cb, float* __restrict__ cbf, float* __restrict__ cn2,
    const int* __restrict__ flag) {
  __shared__ float sred[256];
  int r = blockIdx.x, t = threadIdx.x;
  int isbf = *flag;
  size_t base = (size_t)r * ND;
  float a0 = ldv(cb, base + t, isbf);
  float a1 = ldv(cb, base + t + 256, isbf);
  float a2 = ldv(cb, base + t + 512, isbf);
  float* o = cbf + base;
  o[t] = a0; o[t + 256] = a1; o[t + 512] = a2;
  float ss = blockReduceSum256(a0 * a0 + a1 * a1 + a2 * a2, sred);
  if (t == 0) cn2[r] = ss;
}

// ---------------- VQ: fp32 distances, per-row top-16 candidates -------------
__global__ __launch_bounds__(256) void k_vq_topk(
    const float* __restrict__ z, const float* __restrict__ cbf,
    const float* __restrict__ xn2, const float* __restrict__ cn2,
    int* __restrict__ cand) {
  __shared__ float xq[16 * 772];
  int tid = threadIdx.x;
  int r0 = blockIdx.x * 16;
  for (int q = 0; q < 16; q++)
    for (int d = tid; d < ND; d += 256)
      xq[q * 772 + d] = z[(size_t)(r0 + q) * ND + d];
  __syncthreads();

  int q = tid >> 4, s = tid & 15;
  const float4* xv4 = (const float4*)(xq + q * 772);
  float xnorm = xn2[r0 + q];

  float bestv[16]; int besti[16];
  #pragma unroll
  for (int j = 0; j < 16; j++) { bestv[j] = 3.4e38f; besti[j] = 0; }
  float wv = 3.4e38f; int wslot = 0;

  for (int i = 0; i < 512; i++) {
    int k = (s << 9) + i;
    const float4* c4 = (const float4*)(cbf + (size_t)k * ND);
    float acc = 0.f;
    #pragma unroll 8
    for (int d4 = 0; d4 < ND / 4; d4++) {
      float4 cv = c4[d4]; float4 xv = xv4[d4];
      acc += xv.x * cv.x + xv.y * cv.y + xv.z * cv.z + xv.w * cv.w;
    }
    float dt = xnorm + cn2[k] - 2.f * acc;
    if (dt < wv) {
      #pragma unroll
      for (int j = 0; j < 16; j++)
        if (j == wslot) { bestv[j] = dt; besti[j] = k; }
      wv = bestv[0]; wslot = 0;
      #pragma unroll
      for (int j = 1; j < 16; j++)
        if (bestv[j] > wv) { wv = bestv[j]; wslot = j; }
    }
  }
  __syncthreads();
  float* svals = xq;
  int*   sidx  = (int*)(xq + 4096);
  #pragma unroll
  for (int j = 0; j < 16; j++) {
    svals[q * 256 + s * 16 + j] = bestv[j];
    sidx [q * 256 + s * 16 + j] = besti[j];
  }
  __syncthreads();
  if (tid < 16) {
    float bv[16]; int bi[16]; float w = 3.4e38f; int wsl = 0;
    #pragma unroll
    for (int j = 0; j < 16; j++) { bv[j] = 3.4e38f; bi[j] = 0; }
    const float* sv = svals + tid * 256;
    const int*   si = sidx  + tid * 256;
    for (int i = 0; i < 256; i++) {
      float dv = sv[i];
      if (dv < w) {
        int ii = si[i];
        #pragma unroll
        for (int j = 0; j < 16; j++)
          if (j == wsl) { bv[j] = dv; bi[j] = ii; }
        w = bv[0]; wsl = 0;
        #pragma unroll
        for (int j = 1; j < 16; j++)
          if (bv[j] > w) { w = bv[j]; wsl = j; }
      }
    }
    int* o = cand + (size_t)(r0 + tid) * 16;
    #pragma unroll
    for (int j = 0; j < 16; j++) o[j] = bi[j];
  }
}

// ---------------- threefry2x32, key (0, 42) ----------------
__device__ __forceinline__ void threefry2x32_042(u32 c0, u32 c1, u32& o0, u32& o1) {
  const u32 K0 = 0u, K1 = 42u, K2 = 0u ^ 42u ^ 0x1BD11BDAu;
  u32 x0 = c0 + K0, x1 = c1 + K1;
  #define TF_R(r) { x0 += x1; x1 = (x1 << (r)) | (x1 >> (32 - (r))); x1 ^= x0; }
  TF_R(13) TF_R(15) TF_R(26) TF_R(6)   x0 += K1; x1 += K2 + 1u;
  TF_R(17) TF_R(29) TF_R(16) TF_R(24)  x0 += K2; x1 += K0 + 2u;
  TF_R(13) TF_R(15) TF_R(26) TF_R(6)   x0 += K0; x1 += K1 + 3u;
  TF_R(17) TF_R(29) TF_R(16) TF_R(24)  x0 += K1; x1 += K2 + 4u;
  TF_R(13) TF_R(15) TF_R(26) TF_R(6)   x0 += K2; x1 += K0 + 5u;
  #undef TF_R
  o0 = x0; o1 = x1;
}

__device__ __forceinline__ u32 jax_bits(u32 e) {
  u32 b0, b1;
#if THREEFRY_PARTITIONABLE
  threefry2x32_042(0u, e, b0, b1);
  return b0 ^ b1;
#else
  const u32 HALF = (u32)(NTOK * 10 / 2);
  if (e < HALF) { threefry2x32_042(e, e + HALF, b0, b1); return b0; }
  else          { threefry2x32_042(e - HALF, e, b0, b1); return b1; }
#endif
}

// ---------------- VQ refine (fp64) + gumbel choose + write quantized --------
__global__ __launch_bounds__(64) void k_vq_choose(
    const float* __restrict__ z, const float* __restrict__ cbf,
    const int* __restrict__ cand, float* __restrict__ h) {
  __shared__ double s_xc[64], s_c2[64];
  __shared__ double dvals[16]; __shared__ int didx[16];
  __shared__ int s_enc;
  __shared__ double s_x2v;
  int r = blockIdx.x, t = threadIdx.x;
  int c = t >> 2, p = t & 3;
  int idx = cand[(size_t)r * 16 + c];
  const float* xr = z + (size_t)r * ND;
  const float* cr = cbf + (size_t)idx * ND;
  double xc = 0.0, c2 = 0.0;
  for (int d = p * 192; d < p * 192 + 192; d++) {
    double xv = (double)xr[d], cv = (double)cr[d];
    xc += xv * cv; c2 += cv * cv;
  }
  s_xc[t] = xc; s_c2[t] = c2;
  __syncthreads();
  if (t == 0) {
    double sx2 = 0;
    for (int d = 0; d < ND; d++) { double xv = (double)xr[d]; sx2 += xv * xv; }
    s_x2v = sx2;
  }
  __syncthreads();
  if (t < 16) {
    double sxc = 0, sc2 = 0;
    for (int pp = 0; pp < 4; pp++) { sxc += s_xc[t * 4 + pp]; sc2 += s_c2[t * 4 + pp]; }
    dvals[t] = s_x2v + sc2 - 2.0 * sxc;
    didx[t]  = cand[(size_t)r * 16 + t];
  }
  __syncthreads();
  if (t == 0) {
    double dv[16]; int di[16];
    for (int j = 0; j < 16; j++) { dv[j] = dvals[j]; di[j] = didx[j]; }
    for (int a = 1; a < 16; a++) {          // stable ascending (d, idx)
      double vv = dv[a]; int ii = di[a]; int b = a;
      while (b > 0 && (dv[b-1] > vv || (dv[b-1] == vv && di[b-1] > ii))) {
        dv[b] = dv[b-1]; di[b] = di[b-1]; b--;
      }
      dv[b] = vv; di[b] = ii;
    }
    double bestsc = -1e300; int bestj = 0;
    for (int j = 0; j < 10; j++) {
      u32 e = (u32)(r * 10 + j);
      u32 bits = jax_bits(e);
      u32 fb = (bits >> 9) | 0x3f800000u;
      float uf = __uint_as_float(fb) - 1.0f;
      float vf = uf + 1e-10f;
      vf = fmaxf(1e-10f, vf);
      double g = -log(-log((double)vf));
      double sc = -dv[j] + g;
      if (sc > bestsc) { bestsc = sc; bestj = j; }
    }
    s_enc = di[bestj];
  }
  __syncthreads();
  int enc = s_enc;
  const float* qv = cbf + (size_t)enc * ND;
  float* hr = h + (size_t)r * ND;
  for (int d = t; d < ND; d += 64) hr[d] = qv[d];
}

// ---------------- GEMM: C = A[M,K]fp32 * Bw[N,K]^T + bias ----------------
// Bw/bias dtype per flag; boff/bioff are element offsets resolved device-side.
__global__ __launch_bounds__(256) void k_gemm_nt(
    const float* __restrict__ A, const void* __restrict__ Bw, u64 boff,
    const void* __restrict__ bias, u64 bioff, void* __restrict__ Cv,
    int M, int N, int Kd, int lda, int ldb, int ldc, int relu, int outIsInputDtype,
    const int* __restrict__ flag) {
  __shared__ float As[16][68];
  __shared__ float Bs[16][68];
  int isbf = *flag;
  int tid = threadIdx.x;
  int tx = tid & 15, ty = tid >> 4;
  int m0 = blockIdx.y * 64, n0 = blockIdx.x * 64;
  int la_m = tid >> 2, la_k = (tid & 3) * 4;
  const float* Aptr = A + (size_t)(m0 + la_m) * lda + la_k;
  const u16*   B16 = (const u16*)Bw + boff + (size_t)(n0 + la_m) * ldb + la_k;
  const float* B32 = (const float*)Bw + boff + (size_t)(n0 + la_m) * ldb + la_k;
  float acc[4][4] = {};
  for (int kt = 0; kt < Kd; kt += 16) {
    float4 av = *(const float4*)(Aptr + kt);
    float b0, b1, b2, b3;
    if (isbf) {
      ushort4 bu = *(const ushort4*)(B16 + kt);
      b0 = b2f(bu.x); b1 = b2f(bu.y); b2 = b2f(bu.z); b3 = b2f(bu.w);
    } else {
      float4 bf4 = *(const float4*)(B32 + kt);
      b0 = bf4.x; b1 = bf4.y; b2 = bf4.z; b3 = bf4.w;
    }
    As[la_k + 0][la_m] = av.x; As[la_k + 1][la_m] = av.y;
    As[la_k + 2][la_m] = av.z; As[la_k + 3][la_m] = av.w;
    Bs[la_k + 0][la_m] = b0; Bs[la_k + 1][la_m] = b1;
    Bs[la_k + 2][la_m] = b2; Bs[la_k + 3][la_m] = b3;
    __syncthreads();
    #pragma unroll
    for (int k = 0; k < 16; k++) {
      float4 a4 = *(const float4*)(&As[k][ty * 4]);
      float4 b4 = *(const float4*)(&Bs[k][tx * 4]);
      float a[4] = {a4.x, a4.y, a4.z, a4.w};
      float b[4] = {b4.x, b4.y, b4.z, b4.w};
      #pragma unroll
      for (int i = 0; i < 4; i++)
        #pragma unroll
        for (int j = 0; j < 4; j++) acc[i][j] += a[i] * b[j];
    }
    __syncthreads();
  }
  float bv[4];
  #pragma unroll
  for (int j = 0; j < 4; j++) bv[j] = ldv(bias, bioff + n0 + tx * 4 + j, isbf);
  #pragma unroll
  for (int i = 0; i < 4; i++) {
    int cm = m0 + ty * 4 + i;
    float v[4];
    #pragma unroll
    for (int j = 0; j < 4; j++) {
      v[j] = acc[i][j] + bv[j];
      if (relu) v[j] = fmaxf(v[j], 0.f);
    }
    if (outIsInputDtype && isbf) {
      u16* Cb = (u16*)Cv;
      ushort4 o4 = { f2b(v[0]), f2b(v[1]), f2b(v[2]), f2b(v[3]) };
      *(ushort4*)(Cb + (size_t)cm * ldc + n0 + tx * 4) = o4;
    } else {
      float* C = (float*)Cv;
      float4 o4 = { v[0], v[1], v[2], v[3] };
      *(float4*)(C + (size_t)cm * ldc + n0 + tx * 4) = o4;
    }
  }
}

// ---------------- flash attention: O = softmax(QK^T/sqrt(dh)+bias) V --------
__global__ __launch_bounds__(256) void k_flash(
    const float* __restrict__ qkv, const int* __restrict__ padf,
    float* __restrict__ attO, int selfmask) {
  __shared__ float Qs[64][97];
  __shared__ float Ks[32][97];
  __shared__ float Vs[32][97];
  __shared__ float Ps[64][33];
  __shared__ float row_m[64], row_l[64], kbias[32];
  int zb = blockIdx.y; int b = zb >> 3, hh = zb & 7;
  int m0 = blockIdx.x * 64;
  int tid = threadIdx.x, tx = tid & 15, ty = tid >> 4;
  const float* Qb = qkv + (size_t)b * NS * (3 * ND) + hh * NDH;
  const float* Kb = Qb + ND;
  const float* Vb = Qb + 2 * ND;
  for (int e = tid; e < 64 * 96; e += 256) {
    int r = e / 96, c = e - r * 96;
    Qs[r][c] = Qb[(size_t)(m0 + r) * (3 * ND) + c];
  }
  if (tid < 64) { row_m[tid] = -3.0e38f; row_l[tid] = 0.f; }
  __syncthreads();
  float o[4][6];
  #pragma unroll
  for (int i = 0; i < 4; i++)
    #pragma unroll
    for (int j = 0; j < 6; j++) o[i][j] = 0.f;
  const float sq = sqrtf(96.0f);

  for (int kt = 0; kt < NS; kt += 32) {
    for (int e = tid; e < 32 * 96; e += 256) {
      int r = e / 96, c = e - r * 96;
      Ks[r][c] = Kb[(size_t)(kt + r) * (3 * ND) + c];
      Vs[r][c] = Vb[(size_t)(kt + r) * (3 * ND) + c];
    }
    if (tid < 32) kbias[tid] = padf[b * NS + kt + tid] ? NEGV : 0.f;
    __syncthreads();

    float s[4][2];
    #pragma unroll
    for (int i = 0; i < 4; i++) { s[i][0] = 0.f; s[i][1] = 0.f; }
    for (int d = 0; d < 96; d++) {
      float b0 = Ks[tx * 2 + 0][d], b1 = Ks[tx * 2 + 1][d];
      #pragma unroll
      for (int i = 0; i < 4; i++) {
        float a = Qs[ty * 4 + i][d];
        s[i][0] += a * b0; s[i][1] += a * b1;
      }
    }
    float mnew[4], alpha[4], lt[4];
    #pragma unroll
    for (int i = 0; i < 4; i++) {
      int qg = m0 + ty * 4 + i;
      #pragma unroll
      for (int j = 0; j < 2; j++) {
        int kg = kt + tx * 2 + j;
        float v = s[i][j] / sq + kbias[tx * 2 + j];
        if (selfmask && kg < qg) v += NEGV;
        s[i][j] = v;
      }
      float mv = fmaxf(s[i][0], s[i][1]);
      #pragma unroll
      for (int off = 1; off < 16; off <<= 1) mv = fmaxf(mv, __shfl_xor(mv, off, 16));
      int r = ty * 4 + i;
      float mo = row_m[r];
      float mn = fmaxf(mo, mv);
      mnew[i] = mn;
      alpha[i] = expf(mo - mn);
      float p0 = expf(s[i][0] - mn), p1 = expf(s[i][1] - mn);
      Ps[r][tx * 2 + 0] = p0; Ps[r][tx * 2 + 1] = p1;
      float ls = p0 + p1;
      #pragma unroll
      for (int off = 1; off < 16; off <<= 1) ls += __shfl_xor(ls, off, 16);
      lt[i] = ls;
    }
    __syncthreads();
    if (tx == 0) {
      #pragma unroll
      for (int i = 0; i < 4; i++) {
        int r = ty * 4 + i;
        row_m[r] = mnew[i];
        row_l[r] = row_l[r] * alpha[i] + lt[i];
      }
    }
    #pragma unroll
    for (int i = 0; i < 4; i++)
      #pragma unroll
      for (int j = 0; j < 6; j++) o[i][j] *= alpha[i];
    for (int k2 = 0; k2 < 32; k2++) {
      float vv[6];
      #pragma unroll
      for (int j = 0; j < 6; j++) vv[j] = Vs[k2][tx * 6 + j];
      #pragma unroll
      for (int i = 0; i < 4; i++) {
        float p = Ps[ty * 4 + i][k2];
        #pragma unroll
        for (int j = 0; j < 6; j++) o[i][j] += p * vv[j];
      }
    }
    __syncthreads();
  }
  #pragma unroll
  for (int i = 0; i < 4; i++) {
    int r = ty * 4 + i;
    float inv = 1.0f / row_l[r];
    float* orow = attO + (size_t)(b * NS + m0 + r) * ND + hh * NDH + tx * 6;
    #pragma unroll
    for (int j = 0; j < 6; j++) orow[j] = o[i][j] * inv;
  }
}

// ---------------- LayerNorm(res + x) -> dst ----------------
__global__ __launch_bounds__(256) void k_ln(
    const float* res, const float* x,
    const void* __restrict__ g, const void* __restrict__ bb, u64 goff,
    float* dst, const int* __restrict__ flag) {
  __shared__ float sred[256];
  int r = blockIdx.x, t = threadIdx.x;
  int isbf = *flag;
  const float* rr = res + (size_t)r * ND;
  const float* xr = x + (size_t)r * ND;
  float v0 = rr[t] + xr[t];
  float v1 = rr[t + 256] + xr[t + 256];
  float v2 = rr[t + 512] + xr[t + 512];
  float S = blockReduceSum256(v0 + v1 + v2, sred);
  float m = S / (float)ND;
  float d0 = v0 - m, d1 = v1 - m, d2 = v2 - m;
  float Q = blockReduceSum256(d0 * d0 + d1 * d1 + d2 * d2, sred);
  float inv = 1.0f / sqrtf(Q / (float)ND + 1e-5f);
  float* o = dst + (size_t)r * ND;
  o[t]       = d0 * inv * ldv(g, goff + t, isbf)       + ldv(bb, goff + t, isbf);
  o[t + 256] = d1 * inv * ldv(g, goff + t + 256, isbf) + ldv(bb, goff + t + 256, isbf);
  o[t + 512] = d2 * inv * ldv(g, goff + t + 512, isbf) + ldv(bb, goff + t + 512, isbf);
}

// ---------------------------------------------------------------------------
extern "C" void kernel_launch(void* const* d_in, const int* in_sizes, int n_in,
                              void* d_out, int out_size, void* d_ws, size_t ws_size,
                              hipStream_t stream) {
  const void* x        = d_in[0];
  const void* cb       = d_in[1];
  const void* sa_in_w  = d_in[2];
  const void* sa_in_b  = d_in[3];
  const void* sa_out_w = d_in[4];
  const void* sa_out_b = d_in[5];
  const void* ca_in_w  = d_in[6];
  const void* ca_in_b  = d_in[7];
  const void* ca_out_w = d_in[8];
  const void* ca_out_b = d_in[9];
  const void* ln1_g = d_in[10]; const void* ln1_b = d_in[11];
  const void* ln2_g = d_in[12]; const void* ln2_b = d_in[13];
  const void* ln3_g = d_in[14]; const void* ln3_b = d_in[15];
  const void* ff_w1 = d_in[16]; const void* ff_b1 = d_in[17];
  const void* ff_w2 = d_in[18]; const void* ff_b2 = d_in[19];
  const void* out_w = d_in[20]; const void* out_b = d_in[21];

  // workspace (fp32), ~177 MB total
  const size_t ZSZ = (size_t)NTOK * ND;
  float* ws   = (float*)d_ws;
  float* z    = ws;                                  // z_e == mem
  float* h    = z + ZSZ;
  float* qkv  = h + ZSZ;                             // 3*ZSZ; ff1 aliases
  float* big  = qkv + 3 * ZSZ;                       // ZSZ: cbf, later attO
  float* tmp  = big + ZSZ;
  float* xn2  = tmp + ZSZ;                           // NTOK
  float* cn2  = xn2 + NTOK;                          // NK
  int*   padf = (int*)(cn2 + NK);                    // NTOK
  int*   cand = padf + NTOK;                         // NTOK*16
  int*   dflag = cand + (size_t)NTOK * 16;           // 1
  float* cbf  = big;
  float* attO = big;
  float* ff1  = qkv;

  dim3 blk(256);

  k_detect   <<<1, 64, 0, stream>>>(x, dflag);
  k_pad_z    <<<NTOK, 256, 0, stream>>>(x, z, xn2, padf, dflag);
  k_cb       <<<NK,   256, 0, stream>>>(cb, cbf, cn2, dflag);
  k_vq_topk  <<<NTOK / 16, 256, 0, stream>>>(z, cbf, xn2, cn2, cand);
  k_vq_choose<<<NTOK, 64, 0, stream>>>(z, cbf, cand, h);

  const u64 WQKV = (u64)3 * ND * ND, WO = (u64)ND * ND;
  const u64 WF1 = (u64)NF * ND, WF2 = (u64)ND * NF;

  for (int l = 0; l < NL; l++) {
    // ---- self-attention ----
    k_gemm_nt<<<dim3(3 * ND / 64, NTOK / 64), blk, 0, stream>>>(
        h, sa_in_w, (u64)l * WQKV, sa_in_b, (u64)l * 3 * ND,
        qkv, NTOK, 3 * ND, ND, ND, ND, 3 * ND, 0, 0, dflag);
    k_flash<<<dim3(NS / 64, NB * NH), blk, 0, stream>>>(qkv, padf, attO, 1);
    k_gemm_nt<<<dim3(ND / 64, NTOK / 64), blk, 0, stream>>>(
        attO, sa_out_w, (u64)l * WO, sa_out_b, (u64)l * ND,
        tmp, NTOK, ND, ND, ND, ND, ND, 0, 0, dflag);
    k_ln<<<NTOK, 256, 0, stream>>>(h, tmp, ln1_g, ln1_b, (u64)l * ND, h, dflag);

    // ---- cross-attention: Q from h, K/V from mem (= z_e) ----
    k_gemm_nt<<<dim3(ND / 64, NTOK / 64), blk, 0, stream>>>(
        h, ca_in_w, (u64)l * WQKV, ca_in_b, (u64)l * 3 * ND,
        qkv, NTOK, ND, ND, ND, ND, 3 * ND, 0, 0, dflag);
    k_gemm_nt<<<dim3(2 * ND / 64, NTOK / 64), blk, 0, stream>>>(
        z, ca_in_w, (u64)l * WQKV + (u64)ND * ND, ca_in_b, (u64)l * 3 * ND + ND,
        qkv + ND, NTOK, 2 * ND, ND, ND, ND, 3 * ND, 0, 0, dflag);
    k_flash<<<dim3(NS / 64, NB * NH), blk, 0, stream>>>(qkv, padf, attO, 0);
    k_gemm_nt<<<dim3(ND / 64, NTOK / 64), blk, 0, stream>>>(
        attO, ca_out_w, (u64)l * WO, ca_out_b, (u64)l * ND,
        tmp, NTOK, ND, ND, ND, ND, ND, 0, 0, dflag);
    k_ln<<<NTOK, 256, 0, stream>>>(h, tmp, ln2_g, ln2_b, (u64)l * ND, h, dflag);

    // ---- feed-forward (ff1 aliases qkv, which is dead here) ----
    k_gemm_nt<<<dim3(NF / 64, NTOK / 64), blk, 0, stream>>>(
        h, ff_w1, (u64)l * WF1, ff_b1, (u64)l * NF,
        ff1, NTOK, NF, ND, ND, ND, NF, 1, 0, dflag);
    k_gemm_nt<<<dim3(ND / 64, NTOK / 64), blk, 0, stream>>>(
        ff1, ff_w2, (u64)l * WF2, ff_b2, (u64)l * ND,
        tmp, NTOK, ND, NF, NF, NF, ND, 0, 0, dflag);
    k_ln<<<NTOK, 256, 0, stream>>>(h, tmp, ln3_g, ln3_b, (u64)l * ND, h, dflag);
  }

  // ---- final projection -> output in input dtype ----
  k_gemm_nt<<<dim3(ND / 64, NTOK / 64), blk, 0, stream>>>(
      h, out_w, 0, out_b, 0, d_out, NTOK, ND, ND, ND, ND, ND, 0, 1, dflag);
}

// Round 4
// 23131.451 us; speedup vs baseline: 1.6694x; 1.6694x over previous
//
#include <hip/hip_runtime.h>
#include <math.h>

// ---------------------------------------------------------------------------
// Model_49675591746044: VQ + 6-layer post-LN transformer decoder.
// Round 4: k_vq_topk rewritten for ILP + occupancy (was 21.5ms latency-bound:
// VALUBusy 10%, 2 blocks/CU, single-acc FMA chain). Rest unchanged from the
// passing round-3 kernel (runtime dtype detection, flash attn, fp32 GEMMs).
// ---------------------------------------------------------------------------

#define THREEFRY_PARTITIONABLE 1

typedef unsigned short u16;
typedef unsigned int   u32;
typedef unsigned long long u64;

constexpr int NB  = 16;
constexpr int NS  = 512;
constexpr int ND  = 768;
constexpr int NK  = 8192;
constexpr int NH  = 8;
constexpr int NL  = 6;
constexpr int NF  = 2048;
constexpr int NTOK = NB * NS;   // 8192
constexpr int NDH  = ND / NH;   // 96
#define NEGV (-1e9f)

__device__ __forceinline__ float b2f(u16 u) { return __uint_as_float(((u32)u) << 16); }
__device__ __forceinline__ u16 f2b(float f) {
  u32 u = __float_as_uint(f);
  u32 r = (u + 0x7FFFu + ((u >> 16) & 1u)) >> 16;
  return (u16)r;
}
__device__ __forceinline__ float ldv(const void* p, size_t i, int isbf) {
  return isbf ? b2f(((const u16*)p)[i]) : ((const float*)p)[i];
}

// ---------------- dtype detection ----------------
__global__ void k_detect(const void* x, int* flag) {
  if (threadIdx.x == 0 && blockIdx.x == 0) {
    const u16* p = (const u16*)x;
    int wild = 0;
    for (int i = 0; i < 1024; i++) {
      u16 u = p[i];
      u32 e = (u >> 7) & 0xFF;
      if (!(u == 0 || u == 0x8000u || (e >= 100 && e <= 134))) wild++;
    }
    *flag = (wild < 64) ? 1 : 0;   // 1 = bf16 inputs
  }
}

// ---------------- reductions (blockDim.x == 256) ----------------
__device__ __forceinline__ float blockReduceSum256(float v, float* s) {
  int t = threadIdx.x;
  s[t] = v; __syncthreads();
  #pragma unroll
  for (int off = 128; off > 0; off >>= 1) {
    if (t < off) s[t] += s[t + off];
    __syncthreads();
  }
  float r = s[0]; __syncthreads();
  return r;
}

// ---------------- pad mask + z_e (fp32) + |x|^2 ----------------
__global__ __launch_bounds__(256) void k_pad_z(
    const void* __restrict__ x, float* __restrict__ z,
    float* __restrict__ xn2, int* __restrict__ padf, const int* __restrict__ flag) {
  __shared__ float sred[256];
  int r = blockIdx.x, t = threadIdx.x;
  int isbf = *flag;
  size_t base = (size_t)r * ND;
  float a0 = ldv(x, base + t, isbf);
  float a1 = ldv(x, base + t + 256, isbf);
  float a2 = ldv(x, base + t + 512, isbf);
  float ss = blockReduceSum256(a0 * a0 + a1 * a1 + a2 * a2, sred);
  int pad = (sqrtf(ss) <= 1e-6f) ? 1 : 0;
  if (pad) { a0 = 0.f; a1 = 0.f; a2 = 0.f; }
  float* zr = z + base;
  zr[t] = a0; zr[t + 256] = a1; zr[t + 512] = a2;
  if (t == 0) { xn2[r] = pad ? 0.f : ss; padf[r] = pad; }
}

// ---------------- codebook -> fp32 copy + |c|^2 ----------------
__global__ __launch_bounds__(256) void k_cb(
    const void* __restrict__ cb, float* __restrict__ cbf, float* __restrict__ cn2,
    const int* __restrict__ flag) {
  __shared__ float sred[256];
  int r = blockIdx.x, t = threadIdx.x;
  int isbf = *flag;
  size_t base = (size_t)r * ND;
  float a0 = ldv(cb, base + t, isbf);
  float a1 = ldv(cb, base + t + 256, isbf);
  float a2 = ldv(cb, base + t + 512, isbf);
  float* o = cbf + base;
  o[t] = a0; o[t + 256] = a1; o[t + 512] = a2;
  float ss = blockReduceSum256(a0 * a0 + a1 * a1 + a2 * a2, sred);
  if (t == 0) cn2[r] = ss;
}

// ---------------- VQ top-16 candidates -------------------------------------
// 8 queries/block, 1024 blocks (4/CU), 32 KB LDS (xq then merge alias).
// thread: q = tid&7 (adjacent lanes share codebook address -> broadcast),
// s = tid>>3 scans 256 codes, 2 codes x 2 partial accs = 4 indep FMA chains.
#define VQ_INSERT(dt, kk)                                                    \
  if ((dt) < wv) {                                                           \
    _Pragma("unroll")                                                        \
    for (int j = 0; j < 16; j++)                                             \
      if (j == wslot) { bestv[j] = (dt); besti[j] = (kk); }                  \
    wv = bestv[0]; wslot = 0;                                                \
    _Pragma("unroll")                                                        \
    for (int j = 1; j < 16; j++)                                             \
      if (bestv[j] > wv) { wv = bestv[j]; wslot = j; }                       \
  }

__global__ __launch_bounds__(256, 4) void k_vq_topk(
    const float* __restrict__ z, const float* __restrict__ cbf,
    const float* __restrict__ xn2, const float* __restrict__ cn2,
    int* __restrict__ cand) {
  __shared__ float smem[8192];   // 32 KB: xq = 8 x 776, then svals/sidx alias
  int tid = threadIdx.x;
  int r0 = blockIdx.x * 8;
  for (int e = tid; e < 8 * ND; e += 256) {
    int q = e / ND, d = e - q * ND;
    smem[q * 776 + d] = z[(size_t)(r0 + q) * ND + d];
  }
  __syncthreads();

  int q = tid & 7, s = tid >> 3;
  const float4* xv4 = (const float4*)(smem + q * 776);
  float xnorm = xn2[r0 + q];

  float bestv[16]; int besti[16];
  #pragma unroll
  for (int j = 0; j < 16; j++) { bestv[j] = 3.4e38f; besti[j] = 0; }
  float wv = 3.4e38f; int wslot = 0;

  int base = s * 256;
  for (int i = 0; i < 256; i += 2) {
    int ka = base + i;
    const float4* c4a = (const float4*)(cbf + (size_t)ka * ND);
    const float4* c4b = (const float4*)(cbf + (size_t)(ka + 1) * ND);
    float a0 = 0.f, a1 = 0.f, b0 = 0.f, b1 = 0.f;
    #pragma unroll 4
    for (int d8 = 0; d8 < 96; d8++) {
      float4 x0 = xv4[2 * d8], x1 = xv4[2 * d8 + 1];
      float4 ca0 = c4a[2 * d8], ca1 = c4a[2 * d8 + 1];
      float4 cb0 = c4b[2 * d8], cb1 = c4b[2 * d8 + 1];
      a0 += x0.x * ca0.x + x0.y * ca0.y + x0.z * ca0.z + x0.w * ca0.w;
      a1 += x1.x * ca1.x + x1.y * ca1.y + x1.z * ca1.z + x1.w * ca1.w;
      b0 += x0.x * cb0.x + x0.y * cb0.y + x0.z * cb0.z + x0.w * cb0.w;
      b1 += x1.x * cb1.x + x1.y * cb1.y + x1.z * cb1.z + x1.w * cb1.w;
    }
    float dta = xnorm + cn2[ka] - 2.f * (a0 + a1);
    float dtb = xnorm + cn2[ka + 1] - 2.f * (b0 + b1);
    VQ_INSERT(dta, ka)
    VQ_INSERT(dtb, ka + 1)
  }
  __syncthreads();
  float* svals = smem;               // 8*512 floats
  int*   sidx  = (int*)(smem + 4096);
  #pragma unroll
  for (int j = 0; j < 16; j++) {
    svals[q * 512 + s * 16 + j] = bestv[j];
    sidx [q * 512 + s * 16 + j] = besti[j];
  }
  __syncthreads();
  if (tid < 8) {
    float bv[16]; int bi[16]; float w = 3.4e38f; int wsl = 0;
    #pragma unroll
    for (int j = 0; j < 16; j++) { bv[j] = 3.4e38f; bi[j] = 0; }
    const float* sv = svals + tid * 512;
    const int*   si = sidx  + tid * 512;
    for (int i = 0; i < 512; i++) {
      float dv = sv[i];
      if (dv < w) {
        int ii = si[i];
        #pragma unroll
        for (int j = 0; j < 16; j++)
          if (j == wsl) { bv[j] = dv; bi[j] = ii; }
        w = bv[0]; wsl = 0;
        #pragma unroll
        for (int j = 1; j < 16; j++)
          if (bv[j] > w) { w = bv[j]; wsl = j; }
      }
    }
    int* o = cand + (size_t)(r0 + tid) * 16;
    #pragma unroll
    for (int j = 0; j < 16; j++) o[j] = bi[j];
  }
}

// ---------------- threefry2x32, key (0, 42) ----------------
__device__ __forceinline__ void threefry2x32_042(u32 c0, u32 c1, u32& o0, u32& o1) {
  const u32 K0 = 0u, K1 = 42u, K2 = 0u ^ 42u ^ 0x1BD11BDAu;
  u32 x0 = c0 + K0, x1 = c1 + K1;
  #define TF_R(r) { x0 += x1; x1 = (x1 << (r)) | (x1 >> (32 - (r))); x1 ^= x0; }
  TF_R(13) TF_R(15) TF_R(26) TF_R(6)   x0 += K1; x1 += K2 + 1u;
  TF_R(17) TF_R(29) TF_R(16) TF_R(24)  x0 += K2; x1 += K0 + 2u;
  TF_R(13) TF_R(15) TF_R(26) TF_R(6)   x0 += K0; x1 += K1 + 3u;
  TF_R(17) TF_R(29) TF_R(16) TF_R(24)  x0 += K1; x1 += K2 + 4u;
  TF_R(13) TF_R(15) TF_R(26) TF_R(6)   x0 += K2; x1 += K0 + 5u;
  #undef TF_R
  o0 = x0; o1 = x1;
}

__device__ __forceinline__ u32 jax_bits(u32 e) {
  u32 b0, b1;
#if THREEFRY_PARTITIONABLE
  threefry2x32_042(0u, e, b0, b1);
  return b0 ^ b1;
#else
  const u32 HALF = (u32)(NTOK * 10 / 2);
  if (e < HALF) { threefry2x32_042(e, e + HALF, b0, b1); return b0; }
  else          { threefry2x32_042(e - HALF, e, b0, b1); return b1; }
#endif
}

// ---------------- VQ refine (fp64) + gumbel choose + write quantized --------
__global__ __launch_bounds__(64) void k_vq_choose(
    const float* __restrict__ z, const float* __restrict__ cbf,
    const int* __restrict__ cand, float* __restrict__ h) {
  __shared__ double s_xc[64], s_c2[64];
  __shared__ double dvals[16]; __shared__ int didx[16];
  __shared__ int s_enc;
  __shared__ double s_x2v;
  int r = blockIdx.x, t = threadIdx.x;
  int c = t >> 2, p = t & 3;
  int idx = cand[(size_t)r * 16 + c];
  const float* xr = z + (size_t)r * ND;
  const float* cr = cbf + (size_t)idx * ND;
  double xc = 0.0, c2 = 0.0;
  for (int d = p * 192; d < p * 192 + 192; d++) {
    double xv = (double)xr[d], cv = (double)cr[d];
    xc += xv * cv; c2 += cv * cv;
  }
  s_xc[t] = xc; s_c2[t] = c2;
  __syncthreads();
  if (t == 0) {
    double sx2 = 0;
    for (int d = 0; d < ND; d++) { double xv = (double)xr[d]; sx2 += xv * xv; }
    s_x2v = sx2;
  }
  __syncthreads();
  if (t < 16) {
    double sxc = 0, sc2 = 0;
    for (int pp = 0; pp < 4; pp++) { sxc += s_xc[t * 4 + pp]; sc2 += s_c2[t * 4 + pp]; }
    dvals[t] = s_x2v + sc2 - 2.0 * sxc;
    didx[t]  = cand[(size_t)r * 16 + t];
  }
  __syncthreads();
  if (t == 0) {
    double dv[16]; int di[16];
    for (int j = 0; j < 16; j++) { dv[j] = dvals[j]; di[j] = didx[j]; }
    for (int a = 1; a < 16; a++) {
      double vv = dv[a]; int ii = di[a]; int b = a;
      while (b > 0 && (dv[b-1] > vv || (dv[b-1] == vv && di[b-1] > ii))) {
        dv[b] = dv[b-1]; di[b] = di[b-1]; b--;
      }
      dv[b] = vv; di[b] = ii;
    }
    double bestsc = -1e300; int bestj = 0;
    for (int j = 0; j < 10; j++) {
      u32 e = (u32)(r * 10 + j);
      u32 bits = jax_bits(e);
      u32 fb = (bits >> 9) | 0x3f800000u;
      float uf = __uint_as_float(fb) - 1.0f;
      float vf = uf + 1e-10f;
      vf = fmaxf(1e-10f, vf);
      double g = -log(-log((double)vf));
      double sc = -dv[j] + g;
      if (sc > bestsc) { bestsc = sc; bestj = j; }
    }
    s_enc = di[bestj];
  }
  __syncthreads();
  int enc = s_enc;
  const float* qv = cbf + (size_t)enc * ND;
  float* hr = h + (size_t)r * ND;
  for (int d = t; d < ND; d += 64) hr[d] = qv[d];
}

// ---------------- GEMM: C = A[M,K]fp32 * Bw[N,K]^T + bias ----------------
__global__ __launch_bounds__(256) void k_gemm_nt(
    const float* __restrict__ A, const void* __restrict__ Bw, u64 boff,
    const void* __restrict__ bias, u64 bioff, void* __restrict__ Cv,
    int M, int N, int Kd, int lda, int ldb, int ldc, int relu, int outIsInputDtype,
    const int* __restrict__ flag) {
  __shared__ float As[16][68];
  __shared__ float Bs[16][68];
  int isbf = *flag;
  int tid = threadIdx.x;
  int tx = tid & 15, ty = tid >> 4;
  int m0 = blockIdx.y * 64, n0 = blockIdx.x * 64;
  int la_m = tid >> 2, la_k = (tid & 3) * 4;
  const float* Aptr = A + (size_t)(m0 + la_m) * lda + la_k;
  const u16*   B16 = (const u16*)Bw + boff + (size_t)(n0 + la_m) * ldb + la_k;
  const float* B32 = (const float*)Bw + boff + (size_t)(n0 + la_m) * ldb + la_k;
  float acc[4][4] = {};
  for (int kt = 0; kt < Kd; kt += 16) {
    float4 av = *(const float4*)(Aptr + kt);
    float b0, b1, b2, b3;
    if (isbf) {
      ushort4 bu = *(const ushort4*)(B16 + kt);
      b0 = b2f(bu.x); b1 = b2f(bu.y); b2 = b2f(bu.z); b3 = b2f(bu.w);
    } else {
      float4 bf4 = *(const float4*)(B32 + kt);
      b0 = bf4.x; b1 = bf4.y; b2 = bf4.z; b3 = bf4.w;
    }
    As[la_k + 0][la_m] = av.x; As[la_k + 1][la_m] = av.y;
    As[la_k + 2][la_m] = av.z; As[la_k + 3][la_m] = av.w;
    Bs[la_k + 0][la_m] = b0; Bs[la_k + 1][la_m] = b1;
    Bs[la_k + 2][la_m] = b2; Bs[la_k + 3][la_m] = b3;
    __syncthreads();
    #pragma unroll
    for (int k = 0; k < 16; k++) {
      float4 a4 = *(const float4*)(&As[k][ty * 4]);
      float4 b4 = *(const float4*)(&Bs[k][tx * 4]);
      float a[4] = {a4.x, a4.y, a4.z, a4.w};
      float b[4] = {b4.x, b4.y, b4.z, b4.w};
      #pragma unroll
      for (int i = 0; i < 4; i++)
        #pragma unroll
        for (int j = 0; j < 4; j++) acc[i][j] += a[i] * b[j];
    }
    __syncthreads();
  }
  float bv[4];
  #pragma unroll
  for (int j = 0; j < 4; j++) bv[j] = ldv(bias, bioff + n0 + tx * 4 + j, isbf);
  #pragma unroll
  for (int i = 0; i < 4; i++) {
    int cm = m0 + ty * 4 + i;
    float v[4];
    #pragma unroll
    for (int j = 0; j < 4; j++) {
      v[j] = acc[i][j] + bv[j];
      if (relu) v[j] = fmaxf(v[j], 0.f);
    }
    if (outIsInputDtype && isbf) {
      u16* Cb = (u16*)Cv;
      ushort4 o4 = { f2b(v[0]), f2b(v[1]), f2b(v[2]), f2b(v[3]) };
      *(ushort4*)(Cb + (size_t)cm * ldc + n0 + tx * 4) = o4;
    } else {
      float* C = (float*)Cv;
      float4 o4 = { v[0], v[1], v[2], v[3] };
      *(float4*)(C + (size_t)cm * ldc + n0 + tx * 4) = o4;
    }
  }
}

// ---------------- flash attention: O = softmax(QK^T/sqrt(dh)+bias) V --------
__global__ __launch_bounds__(256) void k_flash(
    const float* __restrict__ qkv, const int* __restrict__ padf,
    float* __restrict__ attO, int selfmask) {
  __shared__ float Qs[64][97];
  __shared__ float Ks[32][97];
  __shared__ float Vs[32][97];
  __shared__ float Ps[64][33];
  __shared__ float row_m[64], row_l[64], kbias[32];
  int zb = blockIdx.y; int b = zb >> 3, hh = zb & 7;
  int m0 = blockIdx.x * 64;
  int tid = threadIdx.x, tx = tid & 15, ty = tid >> 4;
  const float* Qb = qkv + (size_t)b * NS * (3 * ND) + hh * NDH;
  const float* Kb = Qb + ND;
  const float* Vb = Qb + 2 * ND;
  for (int e = tid; e < 64 * 96; e += 256) {
    int r = e / 96, c = e - r * 96;
    Qs[r][c] = Qb[(size_t)(m0 + r) * (3 * ND) + c];
  }
  if (tid < 64) { row_m[tid] = -3.0e38f; row_l[tid] = 0.f; }
  __syncthreads();
  float o[4][6];
  #pragma unroll
  for (int i = 0; i < 4; i++)
    #pragma unroll
    for (int j = 0; j < 6; j++) o[i][j] = 0.f;
  const float sq = sqrtf(96.0f);

  for (int kt = 0; kt < NS; kt += 32) {
    for (int e = tid; e < 32 * 96; e += 256) {
      int r = e / 96, c = e - r * 96;
      Ks[r][c] = Kb[(size_t)(kt + r) * (3 * ND) + c];
      Vs[r][c] = Vb[(size_t)(kt + r) * (3 * ND) + c];
    }
    if (tid < 32) kbias[tid] = padf[b * NS + kt + tid] ? NEGV : 0.f;
    __syncthreads();

    float s[4][2];
    #pragma unroll
    for (int i = 0; i < 4; i++) { s[i][0] = 0.f; s[i][1] = 0.f; }
    for (int d = 0; d < 96; d++) {
      float b0 = Ks[tx * 2 + 0][d], b1 = Ks[tx * 2 + 1][d];
      #pragma unroll
      for (int i = 0; i < 4; i++) {
        float a = Qs[ty * 4 + i][d];
        s[i][0] += a * b0; s[i][1] += a * b1;
      }
    }
    float mnew[4], alpha[4], lt[4];
    #pragma unroll
    for (int i = 0; i < 4; i++) {
      int qg = m0 + ty * 4 + i;
      #pragma unroll
      for (int j = 0; j < 2; j++) {
        int kg = kt + tx * 2 + j;
        float v = s[i][j] / sq + kbias[tx * 2 + j];
        if (selfmask && kg < qg) v += NEGV;
        s[i][j] = v;
      }
      float mv = fmaxf(s[i][0], s[i][1]);
      #pragma unroll
      for (int off = 1; off < 16; off <<= 1) mv = fmaxf(mv, __shfl_xor(mv, off, 16));
      int r = ty * 4 + i;
      float mo = row_m[r];
      float mn = fmaxf(mo, mv);
      mnew[i] = mn;
      alpha[i] = expf(mo - mn);
      float p0 = expf(s[i][0] - mn), p1 = expf(s[i][1] - mn);
      Ps[r][tx * 2 + 0] = p0; Ps[r][tx * 2 + 1] = p1;
      float ls = p0 + p1;
      #pragma unroll
      for (int off = 1; off < 16; off <<= 1) ls += __shfl_xor(ls, off, 16);
      lt[i] = ls;
    }
    __syncthreads();
    if (tx == 0) {
      #pragma unroll
      for (int i = 0; i < 4; i++) {
        int r = ty * 4 + i;
        row_m[r] = mnew[i];
        row_l[r] = row_l[r] * alpha[i] + lt[i];
      }
    }
    #pragma unroll
    for (int i = 0; i < 4; i++)
      #pragma unroll
      for (int j = 0; j < 6; j++) o[i][j] *= alpha[i];
    for (int k2 = 0; k2 < 32; k2++) {
      float vv[6];
      #pragma unroll
      for (int j = 0; j < 6; j++) vv[j] = Vs[k2][tx * 6 + j];
      #pragma unroll
      for (int i = 0; i < 4; i++) {
        float p = Ps[ty * 4 + i][k2];
        #pragma unroll
        for (int j = 0; j < 6; j++) o[i][j] += p * vv[j];
      }
    }
    __syncthreads();
  }
  #pragma unroll
  for (int i = 0; i < 4; i++) {
    int r = ty * 4 + i;
    float inv = 1.0f / row_l[r];
    float* orow = attO + (size_t)(b * NS + m0 + r) * ND + hh * NDH + tx * 6;
    #pragma unroll
    for (int j = 0; j < 6; j++) orow[j] = o[i][j] * inv;
  }
}

// ---------------- LayerNorm(res + x) -> dst ----------------
__global__ __launch_bounds__(256) void k_ln(
    const float* res, const float* x,
    const void* __restrict__ g, const void* __restrict__ bb, u64 goff,
    float* dst, const int* __restrict__ flag) {
  __shared__ float sred[256];
  int r = blockIdx.x, t = threadIdx.x;
  int isbf = *flag;
  const float* rr = res + (size_t)r * ND;
  const float* xr = x + (size_t)r * ND;
  float v0 = rr[t] + xr[t];
  float v1 = rr[t + 256] + xr[t + 256];
  float v2 = rr[t + 512] + xr[t + 512];
  float S = blockReduceSum256(v0 + v1 + v2, sred);
  float m = S / (float)ND;
  float d0 = v0 - m, d1 = v1 - m, d2 = v2 - m;
  float Q = blockReduceSum256(d0 * d0 + d1 * d1 + d2 * d2, sred);
  float inv = 1.0f / sqrtf(Q / (float)ND + 1e-5f);
  float* o = dst + (size_t)r * ND;
  o[t]       = d0 * inv * ldv(g, goff + t, isbf)       + ldv(bb, goff + t, isbf);
  o[t + 256] = d1 * inv * ldv(g, goff + t + 256, isbf) + ldv(bb, goff + t + 256, isbf);
  o[t + 512] = d2 * inv * ldv(g, goff + t + 512, isbf) + ldv(bb, goff + t + 512, isbf);
}

// ---------------------------------------------------------------------------
extern "C" void kernel_launch(void* const* d_in, const int* in_sizes, int n_in,
                              void* d_out, int out_size, void* d_ws, size_t ws_size,
                              hipStream_t stream) {
  const void* x        = d_in[0];
  const void* cb       = d_in[1];
  const void* sa_in_w  = d_in[2];
  const void* sa_in_b  = d_in[3];
  const void* sa_out_w = d_in[4];
  const void* sa_out_b = d_in[5];
  const void* ca_in_w  = d_in[6];
  const void* ca_in_b  = d_in[7];
  const void* ca_out_w = d_in[8];
  const void* ca_out_b = d_in[9];
  const void* ln1_g = d_in[10]; const void* ln1_b = d_in[11];
  const void* ln2_g = d_in[12]; const void* ln2_b = d_in[13];
  const void* ln3_g = d_in[14]; const void* ln3_b = d_in[15];
  const void* ff_w1 = d_in[16]; const void* ff_b1 = d_in[17];
  const void* ff_w2 = d_in[18]; const void* ff_b2 = d_in[19];
  const void* out_w = d_in[20]; const void* out_b = d_in[21];

  const size_t ZSZ = (size_t)NTOK * ND;
  float* ws   = (float*)d_ws;
  float* z    = ws;
  float* h    = z + ZSZ;
  float* qkv  = h + ZSZ;
  float* big  = qkv + 3 * ZSZ;
  float* tmp  = big + ZSZ;
  float* xn2  = tmp + ZSZ;
  float* cn2  = xn2 + NTOK;
  int*   padf = (int*)(cn2 + NK);
  int*   cand = padf + NTOK;
  int*   dflag = cand + (size_t)NTOK * 16;
  float* cbf  = big;
  float* attO = big;
  float* ff1  = qkv;

  dim3 blk(256);

  k_detect   <<<1, 64, 0, stream>>>(x, dflag);
  k_pad_z    <<<NTOK, 256, 0, stream>>>(x, z, xn2, padf, dflag);
  k_cb       <<<NK,   256, 0, stream>>>(cb, cbf, cn2, dflag);
  k_vq_topk  <<<NTOK / 8, 256, 0, stream>>>(z, cbf, xn2, cn2, cand);
  k_vq_choose<<<NTOK, 64, 0, stream>>>(z, cbf, cand, h);

  const u64 WQKV = (u64)3 * ND * ND, WO = (u64)ND * ND;
  const u64 WF1 = (u64)NF * ND, WF2 = (u64)ND * NF;

  for (int l = 0; l < NL; l++) {
    // ---- self-attention ----
    k_gemm_nt<<<dim3(3 * ND / 64, NTOK / 64), blk, 0, stream>>>(
        h, sa_in_w, (u64)l * WQKV, sa_in_b, (u64)l * 3 * ND,
        qkv, NTOK, 3 * ND, ND, ND, ND, 3 * ND, 0, 0, dflag);
    k_flash<<<dim3(NS / 64, NB * NH), blk, 0, stream>>>(qkv, padf, attO, 1);
    k_gemm_nt<<<dim3(ND / 64, NTOK / 64), blk, 0, stream>>>(
        attO, sa_out_w, (u64)l * WO, sa_out_b, (u64)l * ND,
        tmp, NTOK, ND, ND, ND, ND, ND, 0, 0, dflag);
    k_ln<<<NTOK, 256, 0, stream>>>(h, tmp, ln1_g, ln1_b, (u64)l * ND, h, dflag);

    // ---- cross-attention: Q from h, K/V from mem (= z_e) ----
    k_gemm_nt<<<dim3(ND / 64, NTOK / 64), blk, 0, stream>>>(
        h, ca_in_w, (u64)l * WQKV, ca_in_b, (u64)l * 3 * ND,
        qkv, NTOK, ND, ND, ND, ND, 3 * ND, 0, 0, dflag);
    k_gemm_nt<<<dim3(2 * ND / 64, NTOK / 64), blk, 0, stream>>>(
        z, ca_in_w, (u64)l * WQKV + (u64)ND * ND, ca_in_b, (u64)l * 3 * ND + ND,
        qkv + ND, NTOK, 2 * ND, ND, ND, ND, 3 * ND, 0, 0, dflag);
    k_flash<<<dim3(NS / 64, NB * NH), blk, 0, stream>>>(qkv, padf, attO, 0);
    k_gemm_nt<<<dim3(ND / 64, NTOK / 64), blk, 0, stream>>>(
        attO, ca_out_w, (u64)l * WO, ca_out_b, (u64)l * ND,
        tmp, NTOK, ND, ND, ND, ND, ND, 0, 0, dflag);
    k_ln<<<NTOK, 256, 0, stream>>>(h, tmp, ln2_g, ln2_b, (u64)l * ND, h, dflag);

    // ---- feed-forward (ff1 aliases qkv, dead here) ----
    k_gemm_nt<<<dim3(NF / 64, NTOK / 64), blk, 0, stream>>>(
        h, ff_w1, (u64)l * WF1, ff_b1, (u64)l * NF,
        ff1, NTOK, NF, ND, ND, ND, NF, 1, 0, dflag);
    k_gemm_nt<<<dim3(ND / 64, NTOK / 64), blk, 0, stream>>>(
        ff1, ff_w2, (u64)l * WF2, ff_b2, (u64)l * ND,
        tmp, NTOK, ND, NF, NF, NF, ND, 0, 0, dflag);
    k_ln<<<NTOK, 256, 0, stream>>>(h, tmp, ln3_g, ln3_b, (u64)l * ND, h, dflag);
  }

  // ---- final projection -> output in input dtype ----
  k_gemm_nt<<<dim3(ND / 64, NTOK / 64), blk, 0, stream>>>(
      h, out_w, 0, out_b, 0, d_out, NTOK, ND, ND, ND, ND, ND, 0, 1, dflag);
}